// Round 5
// baseline (1086.666 us; speedup 1.0000x reference)
//
#include <hip/hip_runtime.h>

#define B_N 32
#define T_N 2048
#define K_N 256

typedef float f32x4 __attribute__((ext_vector_type(4)));
typedef int i32x8 __attribute__((ext_vector_type(8)));

// fp8 MX mfma, scales = 1.0 (e8m0 biased 127 in every byte)
#define MFMA8(A, B, C) \
  __builtin_amdgcn_mfma_scale_f32_16x16x128_f8f6f4((A), (B), (C), 0, 0, 0, 0x7F7F7F7F, 0, 0x7F7F7F7F)

// DPP xor-add within a 16-lane row: xor1, xor2, xor4(half-mirror), xor8(mirror)
#define DPP_XOR_ADD(x, CTRL) {                                                  \
    int t_ = __builtin_amdgcn_update_dpp(0, __float_as_int(x), CTRL, 0xF, 0xF, true); \
    x += __int_as_float(t_); }
#define ROW16_SUM(x) { DPP_XOR_ADD(x, 0xB1) DPP_XOR_ADD(x, 0x4E)                \
    DPP_XOR_ADD(x, 0x141) DPP_XOR_ADD(x, 0x140) }

// ---------- K1 fused: rowmax (blocks 0..B*T/4-1) + g8 (next 256 blocks) ----------
__global__ __launch_bounds__(256) void k_prep(const float* __restrict__ y,
                                              float* __restrict__ mx,
                                              const float* __restrict__ trans,
                                              unsigned char* __restrict__ GT) {
  int blk = blockIdx.x;
  if (blk < B_N * T_N / 4) {
    int row = blk * 4 + (threadIdx.x >> 6);
    int l = threadIdx.x & 63;
    const float4* p = (const float4*)(y + (size_t)row * K_N);
    float4 v = p[l];
    float m = fmaxf(fmaxf(v.x, v.y), fmaxf(v.z, v.w));
#pragma unroll
    for (int s = 1; s < 64; s <<= 1) m = fmaxf(m, __shfl_xor(m, s));
    if (l == 0) mx[row] = m;
  } else {
    int j = blk - B_N * T_N / 4;   // output col
    int i = threadIdx.x;           // k index
    float g = __expf(trans[i * K_N + j]) - 1.0f;
    int pk = __builtin_amdgcn_cvt_pk_fp8_f32(g, 0.f, 0, false);
    GT[j * K_N + i] = (unsigned char)(pk & 0xff);
  }
}

// ---------- main sequential forward: one block (4 waves) per batch ----------
// u_j = Sp + v8.g_j (fp8 K=128 mfma);  Sp = f32 sum of previous UNQUANTIZED wv
// (exchanged as 16 row-partials: DPP 16-lane reduce + 1 f32/row in LDS).
// wv_j = (Sp + u_j) * exp(y_j - mx_t - log Sp)  ->  stored v in [0, 1.06] (e4m3).
// Cn accumulates log Sp per step (exact telescoping, R3 math = absmax 0).
__global__ __launch_bounds__(256, 1) void k_crf(
    const float* __restrict__ y, const unsigned char* __restrict__ GT,
    const float* __restrict__ mx, const int* __restrict__ lab,
    const float* __restrict__ trans, float* __restrict__ out) {
  const int b = blockIdx.x;
  const int tid = threadIdx.x;
  const int w = tid >> 6;      // wave: owns cols [64w, 64w+64)
  const int l = tid & 63;
  const int lr = l & 15;       // col within 16-tile
  const int lg = (l >> 4) & 3; // k-subgroup / own col-tile
  const int mycol = w * 64 + lg * 16 + lr;

  alignas(64) __shared__ unsigned char vbuf8[2][K_N];
  alignas(16) __shared__ float redP[2][16];   // 16 row-partials, parity dbuf
  __shared__ float pr[4];

  const float* __restrict__ ybase = y + (size_t)b * T_N * K_N;
  const float* __restrict__ ybl = ybase + mycol;      // per-lane column
  const float* __restrict__ mxb = mx + b * T_N;

  // ---- prologue: path score (point + transition) ----
  {
    float s_pt = 0.f, s_tr = 0.f;
    const int* lb = lab + b * T_N;
    for (int t = tid; t < T_N; t += 256) {
      int lt = lb[t];
      s_pt += ybase[(size_t)t * K_N + lt];
      if (t < T_N - 1) s_tr += trans[lt * K_N + lb[t + 1]];
    }
    float s_ = s_pt + s_tr;
#pragma unroll
    for (int s = 1; s < 64; s <<= 1) s_ += __shfl_xor(s_, s);
    if (l == 0) pr[w] = s_;
  }

  // ---- persistent g8 B-fragments (64 VGPR) ----
  i32x8 Bf[4][2];
#pragma unroll
  for (int tt = 0; tt < 4; ++tt) {
#pragma unroll
    for (int h = 0; h < 2; ++h)
      Bf[tt][h] = *(const i32x8*)(GT + (size_t)(w * 64 + tt * 16 + lr) * K_N + h * 128 + lg * 32);
  }

  // ---- v0 = exp(y0 - mx0): one byte per lane + row-partials ----
  float mx0 = mxb[0];
  {
    float v0 = __expf(ybl[0] - mx0);
    int pk = __builtin_amdgcn_cvt_pk_fp8_f32(v0, 0.f, 0, false);
    vbuf8[0][mycol] = (unsigned char)(pk & 0xff);
    float s0 = v0;
    ROW16_SUM(s0)
    if (lr == 0) redP[0][w * 4 + lg] = s0;
  }

  // ---- rotating 4-deep per-lane y/mx prefetch ----
  float ys[4];
  float mxs[4];
#define PREF(P, TT) { int tp_ = (TT); tp_ = tp_ > (T_N - 1) ? (T_N - 1) : tp_; \
    ys[P] = ybl[(size_t)tp_ * K_N]; mxs[P] = mxb[tp_]; }

  PREF(0, 1) PREF(1, 2) PREF(2, 3) PREF(3, 4)

  float Cn = 0.0f;
  float smx_acc = mx0;

#define BARRIER asm volatile("s_waitcnt lgkmcnt(0)\ns_barrier" ::: "memory");

  BARRIER

#define STEP(TT, P, RB, WB, DO_PREF) {                                         \
    const i32x8* va_ = (const i32x8*)&vbuf8[RB][0];                            \
    i32x8 A0_ = va_[lg];                                                       \
    i32x8 A1_ = va_[4 + lg];                                                   \
    const f32x4* rp_ = (const f32x4*)&redP[((TT) - 1) & 1][0];                 \
    f32x4 p0_ = rp_[0], p1_ = rp_[1], p2_ = rp_[2], p3_ = rp_[3];              \
    f32x4 q_ = (p0_ + p1_) + (p2_ + p3_);                                      \
    float Sp_ = (q_[0] + q_[1]) + (q_[2] + q_[3]);                             \
    float ls_ = __logf(Sp_);                                                   \
    float e_ = __expf(ys[P] - mxs[P] - ls_);                                   \
    smx_acc += mxs[P];                                                         \
    Cn += ls_;                                                                 \
    if (DO_PREF) PREF(P, (TT) + 4)                                             \
    f32x4 z_ = {0.f, 0.f, 0.f, 0.f};                                           \
    f32x4 a0l_ = MFMA8(A0_, Bf[0][0], z_);                                     \
    f32x4 a0h_ = MFMA8(A1_, Bf[0][1], z_);                                     \
    f32x4 a1l_ = MFMA8(A0_, Bf[1][0], z_);                                     \
    f32x4 a1h_ = MFMA8(A1_, Bf[1][1], z_);                                     \
    f32x4 a2l_ = MFMA8(A0_, Bf[2][0], z_);                                     \
    f32x4 a2h_ = MFMA8(A1_, Bf[2][1], z_);                                     \
    f32x4 a3l_ = MFMA8(A0_, Bf[3][0], z_);                                     \
    f32x4 a3h_ = MFMA8(A1_, Bf[3][1], z_);                                     \
    float ol_ = lg == 0 ? a0l_[0] : lg == 1 ? a1l_[0] : lg == 2 ? a2l_[0] : a3l_[0]; \
    float oh_ = lg == 0 ? a0h_[0] : lg == 1 ? a1h_[0] : lg == 2 ? a2h_[0] : a3h_[0]; \
    float wv_ = (Sp_ + (ol_ + oh_)) * e_;                                      \
    int pk_ = __builtin_amdgcn_cvt_pk_fp8_f32(wv_, 0.f, 0, false);             \
    vbuf8[WB][mycol] = (unsigned char)(pk_ & 0xff);                            \
    float ss_ = wv_;                                                           \
    ROW16_SUM(ss_)                                                             \
    if (lr == 0) redP[(TT) & 1][w * 4 + lg] = ss_;                             \
    BARRIER                                                                    \
  }

#pragma unroll 1
  for (int t0 = 1; t0 <= T_N - 7; t0 += 4) {   // t0 = 1,5,...,2041 -> t = 1..2044
    STEP(t0,     0, 0, 1, 1)
    STEP(t0 + 1, 1, 1, 0, 1)
    STEP(t0 + 2, 2, 0, 1, 1)
    STEP(t0 + 3, 3, 1, 0, 1)
  }
  // tail: t = 2045 (P0), 2046 (P1), 2047 (P2)
  STEP(2045, 0, 0, 1, 0)
  STEP(2046, 1, 1, 0, 0)
  STEP(2047, 2, 0, 1, 0)

  // ---- final: log(sum of last partials) + Cn + smx - path ----
  if (tid == 0) {
    const f32x4* rp = (const f32x4*)&redP[1][0];      // 2047 & 1 == 1
    f32x4 q = (rp[0] + rp[1]) + (rp[2] + rp[3]);
    float S = (q[0] + q[1]) + (q[2] + q[3]);
    float path = (pr[0] + pr[1]) + (pr[2] + pr[3]);
    out[b] = __logf(S) + Cn + smx_acc - path;
  }
}

extern "C" void kernel_launch(void* const* d_in, const int* in_sizes, int n_in,
                              void* d_out, int out_size, void* d_ws, size_t ws_size,
                              hipStream_t stream) {
  const float* y = (const float*)d_in[0];
  const float* trans = (const float*)d_in[1];
  const int* lab = (const int*)d_in[2];
  float* out = (float*)d_out;

  // workspace carve (~320 KB)
  float* mx = (float*)d_ws;                                           // B*T f32
  unsigned char* GT = (unsigned char*)d_ws + (size_t)B_N * T_N * 4;   // K*K fp8

  k_prep<<<dim3(B_N * T_N / 4 + K_N), dim3(256), 0, stream>>>(y, mx, trans, GT);
  k_crf<<<dim3(B_N), dim3(256), 0, stream>>>(y, GT, mx, lab, trans, out);
}